// Round 4
// baseline (168.535 us; speedup 1.0000x reference)
//
#include <hip/hip_runtime.h>
#include <hip/hip_bf16.h>
#include <math.h>

#define FDIM 6272
#define LQ   256
#define BN   8
#define UDIM 32
#define BL   (BN*LQ)        // 2048

typedef short  short8 __attribute__((ext_vector_type(8)));
typedef float  f32x4  __attribute__((ext_vector_type(4)));

static __device__ __forceinline__ ushort f2bf(float f) {
    __hip_bfloat16 h = __float2bfloat16(f);
    return *(ushort*)&h;
}

// ---------------------------------------------------------------------------
// Kw: Wtt[u][f] = bf16(Wt[f][u])  (one-shot transpose, L2-resident)
//     + zeros pb (replaces hipMemsetAsync dispatch; same-stream ordering).
// grid 98 x 256.
// ---------------------------------------------------------------------------
__global__ __launch_bounds__(256)
void k_wtt(const float* __restrict__ Wt, ushort* __restrict__ wtt,
           float* __restrict__ pb) {
    const int gid = blockIdx.x * 256 + threadIdx.x;   // 0..25087
    const int u = gid / 784, fg = gid % 784;
    ushort v[8];
    #pragma unroll
    for (int j = 0; j < 8; ++j)
        v[j] = f2bf(Wt[(size_t)(8 * fg + j) * UDIM + u]);
    *(uint4*)(wtt + (size_t)u * FDIM + 8 * fg) = *(uint4*)v;

    if (gid < BL * UDIM / 4)                          // 16384 float4s
        ((float4*)pb)[gid] = make_float4(0.f, 0.f, 0.f, 0.f);
}

// ---------------------------------------------------------------------------
// K1: pb[row][u] = sum_f x[row][f] * Wt[f][u]  via bf16 MFMA 16x16x32.
// Block: 32 rows x 32 u, f-split 7 (K-range 896, BK=32 -> 28 chunks).
// fp32 atomicAdd epilogue onto pb (zeroed by k_wtt).
// grid (64, 7), block 256.
// ---------------------------------------------------------------------------
__global__ __launch_bounds__(256)
void k1_mfma(const float* __restrict__ x, const ushort* __restrict__ wtt,
             float* __restrict__ pb) {
    __shared__ ushort As[32 * 40];
    __shared__ ushort Bs[32 * 40];

    const int t    = threadIdx.x;
    const int row0 = blockIdx.x * 32;
    const int f0   = blockIdx.y * 896;
    const int wv   = t >> 6, lane = t & 63;
    const int n16  = lane & 15, quad = lane >> 4;
    const int m0   = 16 * (wv & 1), n0 = 16 * (wv >> 1);

    const int srow = t >> 3, sg = t & 7;

    f32x4 acc = (f32x4){0.f, 0.f, 0.f, 0.f};

    for (int c = 0; c < 28; ++c) {
        const int kk = f0 + c * 32;
        __syncthreads();
        const float4 xv = *(const float4*)(x + (size_t)(row0 + srow) * FDIM + kk + 4 * sg);
        uint2 pk;
        pk.x = (unsigned)f2bf(xv.x) | ((unsigned)f2bf(xv.y) << 16);
        pk.y = (unsigned)f2bf(xv.z) | ((unsigned)f2bf(xv.w) << 16);
        *(uint2*)(As + srow * 40 + 4 * sg) = pk;
        *(uint2*)(Bs + srow * 40 + 4 * sg) =
            *(const uint2*)(wtt + (size_t)srow * FDIM + kk + 4 * sg);
        __syncthreads();

        const short8 af = *(const short8*)(As + (m0 + n16) * 40 + quad * 8);
        const short8 bf = *(const short8*)(Bs + (n0 + n16) * 40 + quad * 8);
        acc = __builtin_amdgcn_mfma_f32_16x16x32_bf16(af, bf, acc, 0, 0, 0);
    }

    #pragma unroll
    for (int r = 0; r < 4; ++r)
        atomicAdd(&pb[(size_t)(row0 + m0 + quad * 4 + r) * UDIM + n0 + n16], acc[r]);
}

// ---------------------------------------------------------------------------
// K2: a[b,q,:] = softmax_k sigmoid( tanh(p_q + p_k + bh) . Wa + ba ), emit bf16
// ---------------------------------------------------------------------------
__global__ __launch_bounds__(256)
void k2_attn(const float* __restrict__ pb, const float* __restrict__ bh,
             const float* __restrict__ Wa, const float* __restrict__ ba,
             ushort* __restrict__ ab) {
    const int bq = blockIdx.x;
    const int b  = bq >> 8;
    const int k  = threadIdx.x;

    __shared__ float pq_s[UDIM];
    __shared__ float wa_s[UDIM];
    __shared__ float pk_s[LQ * 33];
    __shared__ float red[4];

    if (k < UDIM) {
        pq_s[k] = pb[bq * UDIM + k] + bh[k];
        wa_s[k] = Wa[k];
    }
    const float* pbb = pb + (size_t)b * LQ * UDIM;
    #pragma unroll
    for (int i = 0; i < 32; ++i) {
        int idx = k + i * 256;
        pk_s[(idx >> 5) * 33 + (idx & 31)] = pbb[idx];
    }
    __syncthreads();

    const float* pk = &pk_s[k * 33];
    float s = 0.f;
    #pragma unroll
    for (int u = 0; u < UDIM; ++u)
        s = fmaf(tanhf(pq_s[u] + pk[u]), wa_s[u], s);

    const float alpha = 1.f / (1.f + expf(-(s + ba[0])));
    const float e = expf(alpha);          // sigmoid output in (0,1): exp safe

    float v = e;
    #pragma unroll
    for (int m = 1; m < 64; m <<= 1) v += __shfl_xor(v, m, 64);
    if ((k & 63) == 0) red[k >> 6] = v;
    __syncthreads();
    const float tot = red[0] + red[1] + red[2] + red[3];

    ab[(size_t)bq * LQ + k] = f2bf(e / tot);
}

// ---------------------------------------------------------------------------
// K3 (fused transpose): out[b,q,f] = sum_k a[b,q,k] * x[b,k,f], bf16 MFMA.
// Block = ALL 256 q x 64 f  ->  each x-slice read by exactly one block per b
// (no duplication; K0 eliminated). Per BK=32 chunk: stage x[32k][64f] fp32 ->
// LDS bf16 [f][k] (pack k-pairs; bank-exact 2-way writes = free). A-frags
// (a[q][k], k-contig, L2-hot) loaded directly from global - no LDS.
// Bs rows stride 40 ushorts (5x16B units, odd -> conflict-free b128 frags).
// grid (98 f-tiles, 8 b), block 256 = 4 waves (64 q each). acc 4x4 frags.
// ---------------------------------------------------------------------------
__global__ __launch_bounds__(256, 3)
void k3_fused(const float* __restrict__ x, const ushort* __restrict__ ab,
              float* __restrict__ out) {
    __shared__ ushort Bs[64 * 40];    // 5 KB

    const int t    = threadIdx.x;
    const int f0   = blockIdx.x * 64;
    const int b    = blockIdx.y;
    const int wv   = t >> 6;
    const int lane = t & 63;
    const int n16  = lane & 15;
    const int quad = lane >> 4;

    // staging assignment: f-quad = t>>4 (0..15), k-pair = t&15 (0..15)
    const int g  = t >> 4;
    const int kp = t & 15;

    const float*  xb  = x  + (size_t)b * LQ * FDIM + f0 + 4 * g;
    const ushort* abb = ab + (size_t)b * LQ * LQ;

    f32x4 acc[4][4];
    #pragma unroll
    for (int mf = 0; mf < 4; ++mf)
        #pragma unroll
        for (int nf = 0; nf < 4; ++nf)
            acc[mf][nf] = (f32x4){0.f, 0.f, 0.f, 0.f};

    for (int c = 0; c < 8; ++c) {
        const int kc = c * 32;
        __syncthreads();              // prev chunk's frag reads done
        {   // stage x[kc..kc+31][f0..f0+63] -> Bs[f][k] bf16, k-pairs packed
            const float4 v0 = *(const float4*)(xb + (size_t)(kc + 2 * kp    ) * FDIM);
            const float4 v1 = *(const float4*)(xb + (size_t)(kc + 2 * kp + 1) * FDIM);
            unsigned* bw = (unsigned*)Bs;
            bw[(4 * g + 0) * 20 + kp] = (unsigned)f2bf(v0.x) | ((unsigned)f2bf(v1.x) << 16);
            bw[(4 * g + 1) * 20 + kp] = (unsigned)f2bf(v0.y) | ((unsigned)f2bf(v1.y) << 16);
            bw[(4 * g + 2) * 20 + kp] = (unsigned)f2bf(v0.z) | ((unsigned)f2bf(v1.z) << 16);
            bw[(4 * g + 3) * 20 + kp] = (unsigned)f2bf(v0.w) | ((unsigned)f2bf(v1.w) << 16);
        }
        __syncthreads();

        // A-frags direct from global (L2-hot): q = 64*wv + 16*mf + n16
        short8 af[4];
        #pragma unroll
        for (int mf = 0; mf < 4; ++mf)
            af[mf] = *(const short8*)(abb + (size_t)(64 * wv + 16 * mf + n16) * LQ
                                      + kc + quad * 8);
        #pragma unroll
        for (int nf = 0; nf < 4; ++nf) {
            const short8 bf = *(const short8*)(Bs + (16 * nf + n16) * 40 + quad * 8);
            #pragma unroll
            for (int mf = 0; mf < 4; ++mf)
                acc[mf][nf] = __builtin_amdgcn_mfma_f32_16x16x32_bf16(af[mf], bf, acc[mf][nf], 0, 0, 0);
        }
    }

    // epilogue: row q = 64*wv + 16*mf + quad*4 + r, col f = f0 + 16*nf + n16
    float* ob = out + ((size_t)b * LQ + 64 * wv + quad * 4) * FDIM + f0 + n16;
    #pragma unroll
    for (int mf = 0; mf < 4; ++mf)
        #pragma unroll
        for (int nf = 0; nf < 4; ++nf)
            #pragma unroll
            for (int r = 0; r < 4; ++r)
                ob[(size_t)(16 * mf + r) * FDIM + 16 * nf] = acc[mf][nf][r];
}

// ---------------------------------------------------------------------------
extern "C" void kernel_launch(void* const* d_in, const int* in_sizes, int n_in,
                              void* d_out, int out_size, void* d_ws, size_t ws_size,
                              hipStream_t stream) {
    const float* x  = (const float*)d_in[0];   // [8,256,6272]
    const float* Wt = (const float*)d_in[1];   // [6272,32]
    const float* bh = (const float*)d_in[2];   // [32]
    const float* Wa = (const float*)d_in[3];   // [32,1]
    const float* ba = (const float*)d_in[4];   // [1]
    float* out = (float*)d_out;                // [8,256,6272]

    float*  pb  = (float*)d_ws;                              // 2048*32 fp32   (256 KB)
    ushort* ab  = (ushort*)((char*)d_ws + 262144);           // 8*256*256 bf16 (1 MB)
    ushort* wtt = (ushort*)((char*)d_ws + 262144 + 1048576); // 32*6272 bf16   (400 KB)

    k_wtt<<<98, 256, 0, stream>>>(Wt, wtt, pb);
    k1_mfma<<<dim3(64, 7), 256, 0, stream>>>(x, wtt, pb);
    k2_attn<<<BL, 256, 0, stream>>>(pb, bh, Wa, ba, ab);
    k3_fused<<<dim3(98, 8), 256, 0, stream>>>(x, ab, out);
}

// Round 5
// 163.707 us; speedup vs baseline: 1.0295x; 1.0295x over previous
//
#include <hip/hip_runtime.h>
#include <hip/hip_bf16.h>
#include <math.h>

#define FDIM 6272
#define LQ   256
#define BN   8
#define UDIM 32
#define BL   (BN*LQ)        // 2048

typedef short  short8 __attribute__((ext_vector_type(8)));
typedef float  f32x4  __attribute__((ext_vector_type(4)));

static __device__ __forceinline__ ushort f2bf(float f) {
    __hip_bfloat16 h = __float2bfloat16(f);
    return *(ushort*)&h;
}
static __device__ __forceinline__ unsigned pk2(float a, float b) {
    return (unsigned)f2bf(a) | ((unsigned)f2bf(b) << 16);
}
// raw transcendentals (v_exp_f32 = 2^x); s_nop covers the TRANS-op hazard
static __device__ __forceinline__ float fexp2(float x) {
    float r;
    asm volatile("v_exp_f32 %0, %1 \n s_nop 1" : "=v"(r) : "v"(x));
    return r;
}
static __device__ __forceinline__ float frcp(float x) {
    float r;
    asm volatile("v_rcp_f32 %0, %1 \n s_nop 1" : "=v"(r) : "v"(x));
    return r;
}
static __device__ __forceinline__ float tanh_fast(float v) {
    // tanh(v) = 1 - 2/(1 + 2^(2v/ln2));  monotone-safe at |v| large
    return 1.f - 2.f * frcp(1.f + fexp2(v * 2.88539008177793f));
}

// ---------------------------------------------------------------------------
// Kw: Wtt[u][f] = bf16(Wt[f][u]) + zero pb. grid 98 x 256.
// ---------------------------------------------------------------------------
__global__ __launch_bounds__(256)
void k_wtt(const float* __restrict__ Wt, ushort* __restrict__ wtt,
           float* __restrict__ pb) {
    const int gid = blockIdx.x * 256 + threadIdx.x;   // 0..25087
    const int u = gid / 784, fg = gid % 784;
    ushort v[8];
    #pragma unroll
    for (int j = 0; j < 8; ++j)
        v[j] = f2bf(Wt[(size_t)(8 * fg + j) * UDIM + u]);
    *(uint4*)(wtt + (size_t)u * FDIM + 8 * fg) = *(uint4*)v;

    if (gid < BL * UDIM / 4)
        ((float4*)pb)[gid] = make_float4(0.f, 0.f, 0.f, 0.f);
}

// ---------------------------------------------------------------------------
// K1: pb[row][u] += sum_f x[row][f]*Wt[f][u], bf16 MFMA — NO LDS, NO barriers.
// Both fragments loaded direct from global in MFMA operand order:
//   A: lane(n16=m,quad): x[(row0+n16)*FDIM + kk + quad*8 ..+7]  (2x float4)
//   B: wtt[(u0+n16)*FDIM + kk + quad*8]                         (1x 16B)
// Wave = 16 rows x 16 u x K-range 896; block 256 covers 32x32.
// grid (64 row-tiles, 7 f-splits). fp32 atomicAdd epilogue (pb zeroed by Kw).
// ---------------------------------------------------------------------------
__global__ __launch_bounds__(256)
void k1_mfma(const float* __restrict__ x, const ushort* __restrict__ wtt,
             float* __restrict__ pb) {
    const int t    = threadIdx.x;
    const int wv   = t >> 6, lane = t & 63;
    const int n16  = lane & 15, quad = lane >> 4;
    const int row0 = blockIdx.x * 32 + 16 * (wv & 1);
    const int u0   = 16 * (wv >> 1);
    const int f0   = blockIdx.y * 896;

    const float*  xr = x   + (size_t)(row0 + n16) * FDIM + f0 + quad * 8;
    const ushort* wr = wtt + (size_t)(u0   + n16) * FDIM + f0 + quad * 8;

    f32x4 acc = (f32x4){0.f, 0.f, 0.f, 0.f};

    #pragma unroll 4
    for (int c = 0; c < 28; ++c) {
        const float4 a0 = *(const float4*)(xr + c * 32);
        const float4 a1 = *(const float4*)(xr + c * 32 + 4);
        short8 af;
        af[0] = (short)f2bf(a0.x); af[1] = (short)f2bf(a0.y);
        af[2] = (short)f2bf(a0.z); af[3] = (short)f2bf(a0.w);
        af[4] = (short)f2bf(a1.x); af[5] = (short)f2bf(a1.y);
        af[6] = (short)f2bf(a1.z); af[7] = (short)f2bf(a1.w);
        const short8 bf = *(const short8*)(wr + c * 32);
        acc = __builtin_amdgcn_mfma_f32_16x16x32_bf16(af, bf, acc, 0, 0, 0);
    }

    #pragma unroll
    for (int r = 0; r < 4; ++r)
        atomicAdd(&pb[(size_t)(row0 + quad * 4 + r) * UDIM + u0 + n16], acc[r]);
}

// ---------------------------------------------------------------------------
// K2: a[b,q,:] = softmax_k sigmoid( tanh(p_q+p_k+bh).Wa + ba ), fast-tanh.
// pq served from the staged pk_s tile (q is a row of the same batch).
// ---------------------------------------------------------------------------
__global__ __launch_bounds__(256)
void k2_attn(const float* __restrict__ pb, const float* __restrict__ bh,
             const float* __restrict__ Wa, const float* __restrict__ ba,
             ushort* __restrict__ ab) {
    const int bq = blockIdx.x;
    const int b  = bq >> 8, q = bq & 255;
    const int k  = threadIdx.x;

    __shared__ float pk_s[LQ * 33];
    __shared__ float pq_s[UDIM];
    __shared__ float wa_s[UDIM];
    __shared__ float red[4];

    if (k < UDIM) wa_s[k] = Wa[k];
    const float* pbb = pb + (size_t)b * LQ * UDIM;
    #pragma unroll
    for (int i = 0; i < 32; ++i) {
        int idx = k + i * 256;
        pk_s[(idx >> 5) * 33 + (idx & 31)] = pbb[idx];
    }
    __syncthreads();
    if (k < UDIM) pq_s[k] = pk_s[q * 33 + k] + bh[k];
    __syncthreads();

    const float* pk = &pk_s[k * 33];
    float s = 0.f;
    #pragma unroll
    for (int u = 0; u < UDIM; ++u)
        s = fmaf(tanh_fast(pq_s[u] + pk[u]), wa_s[u], s);

    const float alpha = frcp(1.f + fexp2(-(s + ba[0]) * 1.44269504088896f));
    const float e = fexp2(alpha * 1.44269504088896f);  // sigmoid in (0,1): safe

    float v = e;
    #pragma unroll
    for (int m = 1; m < 64; m <<= 1) v += __shfl_xor(v, m, 64);
    if ((k & 63) == 0) red[k >> 6] = v;
    __syncthreads();
    const float tot = red[0] + red[1] + red[2] + red[3];

    ab[(size_t)bq * LQ + k] = f2bf(e * frcp(tot));
}

// ---------------------------------------------------------------------------
// K3: out[b,q,f] = sum_k a[b,q,k]*x[b,k,f], bf16 MFMA, fused transpose,
// BK=64 double-buffered LDS (ONE barrier per chunk; next chunk's global
// loads in flight across current chunk's MFMAs). A-frags direct from global.
// Bs rows stride 72 ushort (9x16B, odd -> conflict-free b128 frags); staging
// writes land 2 lanes/bank (free). grid (98 f-tiles, 8 b), block 256.
// ---------------------------------------------------------------------------
__global__ __launch_bounds__(256)
void k3_fused(const float* __restrict__ x, const ushort* __restrict__ ab,
              float* __restrict__ out) {
    __shared__ ushort Bs[2][64 * 72];    // 2 x 9 KB

    const int t    = threadIdx.x;
    const int f0   = blockIdx.x * 64;
    const int b    = blockIdx.y;
    const int wv   = t >> 6;
    const int lane = t & 63;
    const int n16  = lane & 15;
    const int quad = lane >> 4;
    const int g    = t >> 4;             // f-quad 0..15
    const int kp   = t & 15;             // k-pair slot 0..15 (handles kp, kp+16)

    const float*  xb  = x  + (size_t)b * LQ * FDIM + f0 + 4 * g;
    const ushort* abb = ab + (size_t)b * LQ * LQ;

    f32x4 acc[4][4];
    #pragma unroll
    for (int mf = 0; mf < 4; ++mf)
        #pragma unroll
        for (int nf = 0; nf < 4; ++nf)
            acc[mf][nf] = (f32x4){0.f, 0.f, 0.f, 0.f};

    float4 pv0, pv1, pv2, pv3;
#define LDX(kc) do {                                                   \
        pv0 = *(const float4*)(xb + (size_t)((kc) + 2 * kp     ) * FDIM); \
        pv1 = *(const float4*)(xb + (size_t)((kc) + 2 * kp +  1) * FDIM); \
        pv2 = *(const float4*)(xb + (size_t)((kc) + 2 * kp + 32) * FDIM); \
        pv3 = *(const float4*)(xb + (size_t)((kc) + 2 * kp + 33) * FDIM); \
    } while (0)
#define STX(bufi) do {                                                 \
        unsigned* bw = (unsigned*)(Bs[bufi]);                          \
        bw[(4 * g + 0) * 36 + kp]      = pk2(pv0.x, pv1.x);            \
        bw[(4 * g + 1) * 36 + kp]      = pk2(pv0.y, pv1.y);            \
        bw[(4 * g + 2) * 36 + kp]      = pk2(pv0.z, pv1.z);            \
        bw[(4 * g + 3) * 36 + kp]      = pk2(pv0.w, pv1.w);            \
        bw[(4 * g + 0) * 36 + kp + 16] = pk2(pv2.x, pv3.x);            \
        bw[(4 * g + 1) * 36 + kp + 16] = pk2(pv2.y, pv3.y);            \
        bw[(4 * g + 2) * 36 + kp + 16] = pk2(pv2.z, pv3.z);            \
        bw[(4 * g + 3) * 36 + kp + 16] = pk2(pv2.w, pv3.w);            \
    } while (0)

    LDX(0);
    STX(0);

    for (int c = 0; c < 4; ++c) {
        if (c < 3) LDX((c + 1) * 64);          // prefetch next x-chunk
        // A-frags for this chunk (global, L2-hot; in flight over barrier)
        short8 af[4][2];
        #pragma unroll
        for (int mf = 0; mf < 4; ++mf)
            #pragma unroll
            for (int h = 0; h < 2; ++h)
                af[mf][h] = *(const short8*)(abb
                    + (size_t)(64 * wv + 16 * mf + n16) * LQ
                    + c * 64 + h * 32 + quad * 8);
        __syncthreads();                       // Bs[c&1] ready; prev reads done
        const ushort* bsc = Bs[c & 1];
        #pragma unroll
        for (int h = 0; h < 2; ++h)
            #pragma unroll
            for (int nf = 0; nf < 4; ++nf) {
                const short8 bf = *(const short8*)(bsc + (16 * nf + n16) * 72
                                                   + h * 32 + quad * 8);
                #pragma unroll
                for (int mf = 0; mf < 4; ++mf)
                    acc[mf][nf] = __builtin_amdgcn_mfma_f32_16x16x32_bf16(
                        af[mf][h], bf, acc[mf][nf], 0, 0, 0);
            }
        if (c < 3) STX((c + 1) & 1);           // fill the other buffer
    }
#undef LDX
#undef STX

    float* ob = out + ((size_t)b * LQ + 64 * wv + quad * 4) * FDIM + f0 + n16;
    #pragma unroll
    for (int mf = 0; mf < 4; ++mf)
        #pragma unroll
        for (int nf = 0; nf < 4; ++nf)
            #pragma unroll
            for (int r = 0; r < 4; ++r)
                ob[(size_t)(16 * mf + r) * FDIM + 16 * nf] = acc[mf][nf][r];
}

// ---------------------------------------------------------------------------
extern "C" void kernel_launch(void* const* d_in, const int* in_sizes, int n_in,
                              void* d_out, int out_size, void* d_ws, size_t ws_size,
                              hipStream_t stream) {
    const float* x  = (const float*)d_in[0];   // [8,256,6272]
    const float* Wt = (const float*)d_in[1];   // [6272,32]
    const float* bh = (const float*)d_in[2];   // [32]
    const float* Wa = (const float*)d_in[3];   // [32,1]
    const float* ba = (const float*)d_in[4];   // [1]
    float* out = (float*)d_out;                // [8,256,6272]

    float*  pb  = (float*)d_ws;                              // 2048*32 fp32   (256 KB)
    ushort* ab  = (ushort*)((char*)d_ws + 262144);           // 8*256*256 bf16 (1 MB)
    ushort* wtt = (ushort*)((char*)d_ws + 262144 + 1048576); // 32*6272 bf16   (400 KB)

    k_wtt<<<98, 256, 0, stream>>>(Wt, wtt, pb);
    k1_mfma<<<dim3(64, 7), 256, 0, stream>>>(x, wtt, pb);
    k2_attn<<<BL, 256, 0, stream>>>(pb, bh, Wa, ba, ab);
    k3_fused<<<dim3(98, 8), 256, 0, stream>>>(x, ab, out);
}

// Round 7
// 163.119 us; speedup vs baseline: 1.0332x; 1.0036x over previous
//
#include <hip/hip_runtime.h>
#include <hip/hip_bf16.h>
#include <math.h>

#define FDIM 6272
#define LQ   256
#define BN   8
#define UDIM 32
#define BL   (BN*LQ)        // 2048

typedef short  short8 __attribute__((ext_vector_type(8)));
typedef float  f32x4  __attribute__((ext_vector_type(4)));

static __device__ __forceinline__ ushort f2bf(float f) {
    __hip_bfloat16 h = __float2bfloat16(f);
    return *(ushort*)&h;
}
// raw transcendentals (v_exp_f32 = 2^x); s_nop covers the TRANS-op hazard
static __device__ __forceinline__ float fexp2(float x) {
    float r;
    asm volatile("v_exp_f32 %0, %1 \n s_nop 1" : "=v"(r) : "v"(x));
    return r;
}
static __device__ __forceinline__ float frcp(float x) {
    float r;
    asm volatile("v_rcp_f32 %0, %1 \n s_nop 1" : "=v"(r) : "v"(x));
    return r;
}
static __device__ __forceinline__ float tanh_fast(float v) {
    // tanh(v) = 1 - 2/(1 + 2^(2v/ln2))
    return 1.f - 2.f * frcp(1.f + fexp2(v * 2.88539008177793f));
}

// ---------------------------------------------------------------------------
// Kw: Wtt[u][f] = bf16(Wt[f][u]) + zero pb. grid 98 x 256.
// ---------------------------------------------------------------------------
__global__ __launch_bounds__(256)
void k_wtt(const float* __restrict__ Wt, ushort* __restrict__ wtt,
           float* __restrict__ pb) {
    const int gid = blockIdx.x * 256 + threadIdx.x;   // 0..25087
    const int u = gid / 784, fg = gid % 784;
    ushort v[8];
    #pragma unroll
    for (int j = 0; j < 8; ++j)
        v[j] = f2bf(Wt[(size_t)(8 * fg + j) * UDIM + u]);
    *(uint4*)(wtt + (size_t)u * FDIM + 8 * fg) = *(uint4*)v;

    if (gid < BL * UDIM / 4)
        ((float4*)pb)[gid] = make_float4(0.f, 0.f, 0.f, 0.f);
}

// ---------------------------------------------------------------------------
// K1: pb[row][u] += sum_f x[row][f]*Wt[f][u], bf16 MFMA, NO LDS/barriers.
// Fragments direct from global in MFMA operand order. Byproduct: waves 0-1
// store their packed A-frags as xb16[row][f] (each x element exactly once)
// for K3's bf16 staging. grid (64 row-tiles, 7 f-splits), block 256.
// ---------------------------------------------------------------------------
__global__ __launch_bounds__(256)
void k1_mfma(const float* __restrict__ x, const ushort* __restrict__ wtt,
             float* __restrict__ pb, ushort* __restrict__ xb16) {
    const int t    = threadIdx.x;
    const int wv   = t >> 6, lane = t & 63;
    const int n16  = lane & 15, quad = lane >> 4;
    const int row0 = blockIdx.x * 32 + 16 * (wv & 1);
    const int u0   = 16 * (wv >> 1);
    const int f0   = blockIdx.y * 896;

    const float*  xr = x    + (size_t)(row0 + n16) * FDIM + f0 + quad * 8;
    const ushort* wr = wtt  + (size_t)(u0   + n16) * FDIM + f0 + quad * 8;
    ushort*       xw = xb16 + (size_t)(row0 + n16) * FDIM + f0 + quad * 8;

    f32x4 acc = (f32x4){0.f, 0.f, 0.f, 0.f};

    #pragma unroll 4
    for (int c = 0; c < 28; ++c) {
        const float4 a0 = *(const float4*)(xr + c * 32);
        const float4 a1 = *(const float4*)(xr + c * 32 + 4);
        short8 af;
        af[0] = (short)f2bf(a0.x); af[1] = (short)f2bf(a0.y);
        af[2] = (short)f2bf(a0.z); af[3] = (short)f2bf(a0.w);
        af[4] = (short)f2bf(a1.x); af[5] = (short)f2bf(a1.y);
        af[6] = (short)f2bf(a1.z); af[7] = (short)f2bf(a1.w);
        if (wv < 2)                         // waves 2,3 duplicate rows: skip
            *(short8*)(xw + c * 32) = af;
        const short8 bf = *(const short8*)(wr + c * 32);
        acc = __builtin_amdgcn_mfma_f32_16x16x32_bf16(af, bf, acc, 0, 0, 0);
    }

    #pragma unroll
    for (int r = 0; r < 4; ++r)
        atomicAdd(&pb[(size_t)(row0 + quad * 4 + r) * UDIM + u0 + n16], acc[r]);
}

// ---------------------------------------------------------------------------
// K2: a[b,q,:] = softmax_k sigmoid( tanh(p_q+p_k+bh).Wa + ba ), fast-tanh.
// ---------------------------------------------------------------------------
__global__ __launch_bounds__(256)
void k2_attn(const float* __restrict__ pb, const float* __restrict__ bh,
             const float* __restrict__ Wa, const float* __restrict__ ba,
             ushort* __restrict__ ab) {
    const int bq = blockIdx.x;
    const int b  = bq >> 8, q = bq & 255;
    const int k  = threadIdx.x;

    __shared__ float pk_s[LQ * 33];
    __shared__ float pq_s[UDIM];
    __shared__ float wa_s[UDIM];
    __shared__ float red[4];

    if (k < UDIM) wa_s[k] = Wa[k];
    const float* pbb = pb + (size_t)b * LQ * UDIM;
    #pragma unroll
    for (int i = 0; i < 32; ++i) {
        int idx = k + i * 256;
        pk_s[(idx >> 5) * 33 + (idx & 31)] = pbb[idx];
    }
    __syncthreads();
    if (k < UDIM) pq_s[k] = pk_s[q * 33 + k] + bh[k];
    __syncthreads();

    const float* pk = &pk_s[k * 33];
    float s = 0.f;
    #pragma unroll
    for (int u = 0; u < UDIM; ++u)
        s = fmaf(tanh_fast(pq_s[u] + pk[u]), wa_s[u], s);

    const float alpha = frcp(1.f + fexp2(-(s + ba[0]) * 1.44269504088896f));
    const float e = fexp2(alpha * 1.44269504088896f);  // sigmoid in (0,1): safe

    float v = e;
    #pragma unroll
    for (int m = 1; m < 64; m <<= 1) v += __shfl_xor(v, m, 64);
    if ((k & 63) == 0) red[k >> 6] = v;
    __syncthreads();
    const float tot = red[0] + red[1] + red[2] + red[3];

    ab[(size_t)bq * LQ + k] = f2bf(e * frcp(tot));
}

// ---------------------------------------------------------------------------
// K3: out[b,q,f] = sum_k a[b,q,k]*x[b,k,f], bf16 MFMA, staging from xb16
// (bf16: half the fetch bytes of R5, no v_cvt in repack). BK=64 double-
// buffered LDS, one barrier per chunk, prefetch in flight across barrier.
// A-frags direct from global (ab is L2-hot). Bs rows stride 72 ushort
// (9x16B, odd -> conflict-free b128 frags). grid (98 f-tiles, 8 b).
// ---------------------------------------------------------------------------
__global__ __launch_bounds__(256)
void k3_fused(const ushort* __restrict__ xb16, const ushort* __restrict__ ab,
              float* __restrict__ out) {
    __shared__ ushort Bs[2][64 * 72];    // 2 x 9 KB

    const int t    = threadIdx.x;
    const int f0   = blockIdx.x * 64;
    const int b    = blockIdx.y;
    const int wv   = t >> 6;
    const int lane = t & 63;
    const int n16  = lane & 15;
    const int quad = lane >> 4;
    const int g    = t >> 4;             // f-quad 0..15
    const int kp   = t & 15;             // k-pair slot 0..15 (handles kp, kp+16)

    const ushort* xb  = xb16 + (size_t)b * LQ * FDIM + f0 + 4 * g;
    const ushort* abb = ab   + (size_t)b * LQ * LQ;

    f32x4 acc[4][4];
    #pragma unroll
    for (int mf = 0; mf < 4; ++mf)
        #pragma unroll
        for (int nf = 0; nf < 4; ++nf)
            acc[mf][nf] = (f32x4){0.f, 0.f, 0.f, 0.f};

    uint2 r0, r1, r2, r3;                // rows 2kp, 2kp+1, 2kp+32, 2kp+33
#define LDX(kc) do {                                                      \
        r0 = *(const uint2*)(xb + (size_t)((kc) + 2 * kp     ) * FDIM);   \
        r1 = *(const uint2*)(xb + (size_t)((kc) + 2 * kp +  1) * FDIM);   \
        r2 = *(const uint2*)(xb + (size_t)((kc) + 2 * kp + 32) * FDIM);   \
        r3 = *(const uint2*)(xb + (size_t)((kc) + 2 * kp + 33) * FDIM);   \
    } while (0)
    // word(f=4g+j, slot) = lo16(rowA[j]) | hi16<-lo16(rowB[j])
#define STX(bufi) do {                                                    \
        unsigned* bw = (unsigned*)(Bs[bufi]);                             \
        bw[(4 * g + 0) * 36 + kp]      = (r0.x & 0xffffu) | (r1.x << 16); \
        bw[(4 * g + 1) * 36 + kp]      = (r0.x >> 16) | (r1.x & 0xffff0000u); \
        bw[(4 * g + 2) * 36 + kp]      = (r0.y & 0xffffu) | (r1.y << 16); \
        bw[(4 * g + 3) * 36 + kp]      = (r0.y >> 16) | (r1.y & 0xffff0000u); \
        bw[(4 * g + 0) * 36 + kp + 16] = (r2.x & 0xffffu) | (r3.x << 16); \
        bw[(4 * g + 1) * 36 + kp + 16] = (r2.x >> 16) | (r3.x & 0xffff0000u); \
        bw[(4 * g + 2) * 36 + kp + 16] = (r2.y & 0xffffu) | (r3.y << 16); \
        bw[(4 * g + 3) * 36 + kp + 16] = (r2.y >> 16) | (r3.y & 0xffff0000u); \
    } while (0)

    LDX(0);
    STX(0);

    for (int c = 0; c < 4; ++c) {
        if (c < 3) LDX((c + 1) * 64);          // prefetch next x-chunk
        short8 af[4][2];                       // A-frags (global, L2-hot)
        #pragma unroll
        for (int mf = 0; mf < 4; ++mf)
            #pragma unroll
            for (int h = 0; h < 2; ++h)
                af[mf][h] = *(const short8*)(abb
                    + (size_t)(64 * wv + 16 * mf + n16) * LQ
                    + c * 64 + h * 32 + quad * 8);
        __syncthreads();                       // Bs[c&1] ready; prev reads done
        const ushort* bsc = Bs[c & 1];
        #pragma unroll
        for (int h = 0; h < 2; ++h)
            #pragma unroll
            for (int nf = 0; nf < 4; ++nf) {
                const short8 bf = *(const short8*)(bsc + (16 * nf + n16) * 72
                                                   + h * 32 + quad * 8);
                #pragma unroll
                for (int mf = 0; mf < 4; ++mf)
                    acc[mf][nf] = __builtin_amdgcn_mfma_f32_16x16x32_bf16(
                        af[mf][h], bf, acc[mf][nf], 0, 0, 0);
            }
        if (c < 3) STX((c + 1) & 1);           // fill the other buffer
    }
#undef LDX
#undef STX

    float* ob = out + ((size_t)b * LQ + 64 * wv + quad * 4) * FDIM + f0 + n16;
    #pragma unroll
    for (int mf = 0; mf < 4; ++mf)
        #pragma unroll
        for (int nf = 0; nf < 4; ++nf)
            #pragma unroll
            for (int r = 0; r < 4; ++r)
                ob[(size_t)(16 * mf + r) * FDIM + 16 * nf] = acc[mf][nf][r];
}

// ---------------------------------------------------------------------------
extern "C" void kernel_launch(void* const* d_in, const int* in_sizes, int n_in,
                              void* d_out, int out_size, void* d_ws, size_t ws_size,
                              hipStream_t stream) {
    const float* x  = (const float*)d_in[0];   // [8,256,6272]
    const float* Wt = (const float*)d_in[1];   // [6272,32]
    const float* bh = (const float*)d_in[2];   // [32]
    const float* Wa = (const float*)d_in[3];   // [32,1]
    const float* ba = (const float*)d_in[4];   // [1]
    float* out = (float*)d_out;                // [8,256,6272]

    float*  pb   = (float*)d_ws;                               // 2048*32 fp32   (256 KB)
    ushort* ab   = (ushort*)((char*)d_ws + 262144);            // 8*256*256 bf16 (1 MB)
    ushort* wtt  = (ushort*)((char*)d_ws + 262144 + 1048576);  // 32*6272 bf16   (400 KB -> pad 512K)
    ushort* xb16 = (ushort*)((char*)d_ws + 262144 + 1048576 + 524288); // 8*256*6272 bf16 (25.7 MB)

    k_wtt<<<98, 256, 0, stream>>>(Wt, wtt, pb);
    k1_mfma<<<dim3(64, 7), 256, 0, stream>>>(x, wtt, pb, xb16);
    k2_attn<<<BL, 256, 0, stream>>>(pb, bh, Wa, ba, ab);
    k3_fused<<<dim3(98, 8), 256, 0, stream>>>(xb16, ab, out);
}